// Round 7
// baseline (109.039 us; speedup 1.0000x reference)
//
#include <hip/hip_runtime.h>
#include <math.h>

// Problem constants: IMG_SIZE=1024, B=64, G=128, A=3, N=1280, stride=8
#define NBOX     1280
#define BVAL     64
#define GVAL     128
#define NFLOAT   (BVAL * GVAL * GVAL * 15)   // 15,728,640 floats = 62.9 MB
#define NVEC     (NFLOAT / 4)                // 3,932,160 float4
#define SPAN_V4  2048                        // float4 per sweep block (32 KB span)
#define NSWEEP   (NVEC / SPAN_V4)            // 1920 exactly
#define NBLK     (NSWEEP + 1)                // + 1 box block

typedef unsigned long long u64;
#define TAG 0x5A17C0DEull                    // publish tag (poison 0xAAAAAAAA can't spoof)

__device__ __forceinline__ float softplus_f(float z) {
    return fmaxf(z, 0.f) + __logf(1.f + __expf(-fabsf(z)));
}

// R6 post-mortem: polling fusion won (110.5 -> 104.6, as predicted). Remaining
// yolo-in-context ~45-50 µs vs 10 µs BW floor: issue-depth-bound. R5's profile
// of this body showed VGPR_Count=40 — the compiler provably serialized the
// "16 float4 in flight" intent (needs 64 data VGPRs) to ~6 outstanding/wave.
// R7: decouple depth from VGPRs via global_load_lds (async direct-to-LDS,
// zero register cost per outstanding load; compiler never auto-emits it).
// 32 KB stage/block -> 5 blocks/CU -> 160 KB in flight per CU (~2x), one
// barrier (its vmcnt(0) drain = completion guarantee), then the same mod-5
// conf extraction reading LDS.
//
// blockIdx 0        : target build + dedup + gather-adjust (verified exact),
//                     then polling reduce of all partials (R6 mechanism:
//                     per-slot agent-scope relaxed atomics, tag+payload in one
//                     64-bit word — no fences, no same-line serialization).
// blockIdx 1..1920  : noobj sweep, 32 KB async LDS stage + single barrier.
__global__ void __launch_bounds__(256) yolo_fused_kernel(
    const float* __restrict__ yp,
    const float* __restrict__ gbox,
    const float* __restrict__ anch,
    const int*   __restrict__ bidx,
    u64*         __restrict__ slot,
    float*       __restrict__ out)
{
    __shared__ float4 stage[SPAN_V4];        // 32 KB exactly -> 5 blocks/CU
    int*   skey  = (int*)stage;              // block 0 alias: [0,1280) keys
    int*   scnt  = skey + NBOX;              // block 0 alias: 64 counts
    float* swave = (float*)stage;            // reduce scratch (post-consumption)

    const int t = threadIdx.x;
    float acc = 0.f;

    if (blockIdx.x == 0) {
        if (t < BVAL) scnt[t] = 0;
        __syncthreads();

        // ---- phase 1: per-box key (kept in regs too) + batch histogram ----
        int mykey[5];
        #pragma unroll
        for (int k = 0; k < 5; k++) {
            int n = t + k * 256;                     // 5*256 == NBOX exactly
            float4 g = ((const float4*)gbox)[n];
            float gx = g.x * 0.125f;
            float gy = g.y * 0.125f;
            float gw = g.z * 0.125f;
            float gh = g.w * 0.125f;
            int gi = (int)gx, gj = (int)gy;
            int best = 0; float bestr = -1.f;
            #pragma unroll
            for (int a = 0; a < 3; a++) {
                float aw = anch[a * 2 + 0] * 0.125f;
                float ah = anch[a * 2 + 1] * 0.125f;
                float inter = fminf(aw, gw) * fminf(ah, gh);
                float uni   = aw * ah + gw * gh - inter;
                float r     = inter / uni;
                if (r > bestr) { bestr = r; best = a; }   // first-wins ties, like argmax
            }
            int b = bidx[n];
            int key = ((b * 3 + best) * 128 + gj) * 128 + gi;
            skey[n]  = key;
            mykey[k] = key;
            atomicAdd(&scnt[b], 1);                  // LDS atomic — cheap
        }
        __syncthreads();

        // ---- maxseg = max boxes in any batch ----
        if (t < 64) {
            int v = scnt[t];
            #pragma unroll
            for (int off = 32; off > 0; off >>= 1) v = max(v, __shfl_down(v, off, 64));
            if (t == 0) scnt[0] = v;
        }
        __syncthreads();
        const int maxseg = scnt[0];

        // ---- phase 2: dedup, last-write-wins; fixed trip, branch-free ----
        bool win[5];
        #pragma unroll
        for (int k = 0; k < 5; k++) win[k] = true;
        for (int d = 1; d <= maxseg; d++) {
            #pragma unroll
            for (int k = 0; k < 5; k++) {
                int m2 = t + k * 256 + d;
                int mc = m2 < NBOX ? m2 : NBOX - 1;       // clamp (guard below)
                int other = skey[mc];
                if (m2 < NBOX && other == mykey[k]) win[k] = false;
            }
        }

        // ---- phase 3: winners recompute targets + gather pred + accumulate ----
        #pragma unroll
        for (int k = 0; k < 5; k++) {
            if (!win[k]) continue;
            int n = t + k * 256;
            float4 g = ((const float4*)gbox)[n];
            float gx = g.x * 0.125f;
            float gy = g.y * 0.125f;
            float gw = g.z * 0.125f;
            float gh = g.w * 0.125f;
            int gi = (int)gx, gj = (int)gy;
            int best = 0; float bestr = -1.f, baw = 1.f, bah = 1.f;
            #pragma unroll
            for (int a = 0; a < 3; a++) {
                float aw = anch[a * 2 + 0] * 0.125f;
                float ah = anch[a * 2 + 1] * 0.125f;
                float inter = fminf(aw, gw) * fminf(ah, gh);
                float uni   = aw * ah + gw * gh - inter;
                float r     = inter / uni;
                if (r > bestr) { bestr = r; best = a; baw = aw; bah = ah; }
            }
            float tx = gx - (float)gi;
            float ty = gy - (float)gj;
            float tw = __logf(gw / baw);
            float th = __logf(gh / bah);
            int b = bidx[n];
            long base = ((((long)b * GVAL + gj) * GVAL) + gi) * 15 + best * 5;
            float conf = yp[base + 0];
            float px = 1.f / (1.f + __expf(-yp[base + 1]));
            float py = 1.f / (1.f + __expf(-yp[base + 2]));
            float pw = yp[base + 3];
            float ph = yp[base + 4];
            float dx = px - tx, dy = py - ty, dw = pw - tw, dh = ph - th;
            float lp = __logf(1.f + __expf(-fabsf(conf)));
            float sp_pos = fmaxf( conf, 0.f) + lp;   // softplus(conf)
            float sp_neg = fmaxf(-conf, 0.f) + lp;   // softplus(-conf)
            acc += 5.f * (dx * dx + dy * dy + dw * dw + dh * dh)
                 + sp_neg - 0.5f * sp_pos;           // obj minus over-counted noobj
        }
    } else {
        // ---- noobj sweep: async-stage 32 KB to LDS, one barrier, extract ----
        // Per wave: 8 global_load_lds width=16 instrs, wave-uniform LDS base
        // (chunk c = w*8+k -> stage + c*64 float4), per-lane global source
        // (src + c*64 + lane) -> lane data lands at base + lane*16 (linear
        // dest, m104-safe). Zero VGPR cost per outstanding load.
        const float4* src = (const float4*)yp + (long)(blockIdx.x - 1) * SPAN_V4;
        const int w = t >> 6, l = t & 63;
        #pragma unroll
        for (int k = 0; k < 8; k++) {
            int c = w * 8 + k;                       // chunk 0..31, 1 KB each
            const unsigned int* g = (const unsigned int*)(src + c * 64 + l);
            unsigned int* ldsp = (unsigned int*)(stage + c * 64);  // wave-uniform
            __builtin_amdgcn_global_load_lds(
                (const __attribute__((address_space(1))) unsigned int*)g,
                (__attribute__((address_space(3))) unsigned int*)ldsp,
                16, 0, 0);
        }
        __syncthreads();   // compiler drains vmcnt(0) before s_barrier

        // conf at words ≡ 0 (mod 5); float4 m holds one conf at comp j = m % 5
        // (none when j==4); k-step 256 ≡ 1 (mod 5) so j advances by +1.
        int j = (int)(((long)(blockIdx.x - 1) * SPAN_V4 + t) % 5);
        float lacc = 0.f;
        #pragma unroll
        for (int k = 0; k < 8; k++) {
            float4 v = stage[t + k * 256];           // stride-1 b128: conflict-free
            float c  = (j == 0) ? v.x
                     : (j == 1) ? v.y
                     : (j == 2) ? v.z
                     :            v.w;
            float sp = softplus_f(c);
            lacc += (j < 4) ? sp : 0.f;              // j==4: float4 holds no conf
            j = (j == 4) ? 0 : j + 1;
        }
        acc = 0.5f * lacc;
    }

    // ---- block reduction (swave aliases stage; contents already consumed) ----
    __syncthreads();
    #pragma unroll
    for (int off = 32; off > 0; off >>= 1) acc += __shfl_down(acc, off, 64);
    int lane = t & 63, wid = t >> 6;
    if (lane == 0) swave[wid] = acc;
    __syncthreads();
    float bsum = swave[0] + swave[1] + swave[2] + swave[3];

    if (blockIdx.x != 0) {
        if (t == 0) {
            u64 p = ((u64)TAG << 32) | (u64)__float_as_uint(bsum);
            __hip_atomic_store(&slot[blockIdx.x], p,
                               __ATOMIC_RELAXED, __HIP_MEMORY_SCOPE_AGENT);
        }
        return;
    }

    // ---- block 0: polling reduce (order = old final_reduce: i = t + 256*r) ----
    float a2 = 0.f;
    for (int i = t; i < NBLK; i += 256) {
        float term;
        if (i == 0) {
            term = bsum;
        } else {
            u64 v = __hip_atomic_load(&slot[i], __ATOMIC_RELAXED,
                                      __HIP_MEMORY_SCOPE_AGENT);
            while ((unsigned)(v >> 32) != (unsigned)TAG) {
                __builtin_amdgcn_s_sleep(8);
                v = __hip_atomic_load(&slot[i], __ATOMIC_RELAXED,
                                      __HIP_MEMORY_SCOPE_AGENT);
            }
            term = __uint_as_float((unsigned)v);
        }
        a2 += term;
    }
    __syncthreads();
    #pragma unroll
    for (int off = 32; off > 0; off >>= 1) a2 += __shfl_down(a2, off, 64);
    if (lane == 0) swave[wid] = a2;
    __syncthreads();
    if (t == 0) out[0] = swave[0] + swave[1] + swave[2] + swave[3];
}

extern "C" void kernel_launch(void* const* d_in, const int* in_sizes, int n_in,
                              void* d_out, int out_size, void* d_ws, size_t ws_size,
                              hipStream_t stream) {
    const float* yp   = (const float*)d_in[0];   // y_pred (B,G,G,15) fp32
    const float* gbox = (const float*)d_in[1];   // ground_bboxes (N,4) fp32
    const float* anch = (const float*)d_in[2];   // anchors (3,2) fp32
    const int*   bidx = (const int*)d_in[3];     // batch_idx (N,) int32
    u64*  slot = (u64*)d_ws;                     // NBLK publish slots (15368 B)
    float* outp = (float*)d_out;

    yolo_fused_kernel<<<dim3(NBLK), dim3(256), 0, stream>>>(yp, gbox, anch, bidx,
                                                            slot, outp);
}

// Round 8
// 104.948 us; speedup vs baseline: 1.0390x; 1.0390x over previous
//
#include <hip/hip_runtime.h>
#include <math.h>

// Problem constants: IMG_SIZE=1024, B=64, G=128, A=3, N=1280, stride=8
#define NBOX     1280
#define BVAL     64
#define GVAL     128
#define NFLOAT   (BVAL * GVAL * GVAL * 15)   // 15,728,640 floats = 62.9 MB
#define NVEC     (NFLOAT / 4)                // 3,932,160 float4
#define SPAN_V4  4096                        // float4 per sweep block (64 KB span)
#define NSWEEP   (NVEC / SPAN_V4)            // 960 exactly
#define NBLK     (NSWEEP + 1)                // + 1 box block

typedef unsigned long long u64;
#define TAG 0x5A17C0DEull                    // publish tag (poison 0xAAAAAAAA can't spoof)

__device__ __forceinline__ float softplus_f(float z) {
    return fmaxf(z, 0.f) + __logf(1.f + __expf(-fabsf(z)));
}

// FINAL (R8 = R6 revert, best measured 104.6 µs). Lever ledger:
//   R0-R2 reg-stream: profiled yolo 53.7 -> <41.4 µs, dur_us unmoved
//   R3 nt loads: -8 µs (killed inter-iteration L3 reuse of y_pred)
//   R4 961-block single-generation: occupancy 8->40%, dur_us unmoved
//   R5 cooperative grid.sync: -99 µs (device-fence + 3800-wave spin storm)
//   R6 tagged-slot polling fusion: +6 µs (matched prediction)  <- THIS KERNEL
//   R7 global_load_lds depth: -4.5 µs (depth was ample: 90 KB/CU in flight
//      vs 9.2 KB needed for 6.3 TB/s at 375 ns; theory failed arithmetic)
// Remaining iteration budget is harness-fixed: 41.5 µs 256 MiB poison fill
// (81% HBM write peak), restore memsets, graph gaps, and a cold 63 MB read
// whose bytes are irreducible (conf words every 20 B -> every line touched).
//
// blockIdx 0       : target build + dedup (fixed-trip, branch-free) + gather-
//                    adjust, then polling reduce of all partials.
// blockIdx 1..960  : noobj sweep, single-generation register streaming
//                    (16 float4 loads/thread up front, 64 KB span/block,
//                    ~3.75 blocks/CU all co-resident -> no block churn).
__device__ __forceinline__ float yolo_body(
    const float* __restrict__ yp,
    const float* __restrict__ gbox,
    const float* __restrict__ anch,
    const int*   __restrict__ bidx)
{
    __shared__ int skey[NBOX];   // box keys (block 0 only)
    __shared__ int scnt[BVAL];   // per-batch counts; scnt[0] reused for maxseg

    const int t = threadIdx.x;
    float acc = 0.f;

    if (blockIdx.x == 0) {
        if (t < BVAL) scnt[t] = 0;
        __syncthreads();

        // ---- phase 1: per-box key (kept in regs too) + batch histogram ----
        int mykey[5];
        #pragma unroll
        for (int k = 0; k < 5; k++) {
            int n = t + k * 256;                     // 5*256 == NBOX exactly
            float4 g = ((const float4*)gbox)[n];
            float gx = g.x * 0.125f;
            float gy = g.y * 0.125f;
            float gw = g.z * 0.125f;
            float gh = g.w * 0.125f;
            int gi = (int)gx, gj = (int)gy;
            int best = 0; float bestr = -1.f;
            #pragma unroll
            for (int a = 0; a < 3; a++) {
                float aw = anch[a * 2 + 0] * 0.125f;
                float ah = anch[a * 2 + 1] * 0.125f;
                float inter = fminf(aw, gw) * fminf(ah, gh);
                float uni   = aw * ah + gw * gh - inter;
                float r     = inter / uni;
                if (r > bestr) { bestr = r; best = a; }   // first-wins ties, like argmax
            }
            int b = bidx[n];
            int key = ((b * 3 + best) * 128 + gj) * 128 + gi;
            skey[n]  = key;
            mykey[k] = key;
            atomicAdd(&scnt[b], 1);                  // LDS atomic — cheap
        }
        __syncthreads();

        // ---- maxseg = max boxes in any batch (bound on duplicate-pair distance) ----
        if (t < 64) {
            int v = scnt[t];
            #pragma unroll
            for (int off = 32; off > 0; off >>= 1) v = max(v, __shfl_down(v, off, 64));
            if (t == 0) scnt[0] = v;
        }
        __syncthreads();
        const int maxseg = scnt[0];

        // ---- phase 2: dedup, last-write-wins; fixed trip count, branch-free ----
        bool win[5];
        #pragma unroll
        for (int k = 0; k < 5; k++) win[k] = true;
        for (int d = 1; d <= maxseg; d++) {
            #pragma unroll
            for (int k = 0; k < 5; k++) {
                int m2 = t + k * 256 + d;
                int mc = m2 < NBOX ? m2 : NBOX - 1;       // clamp (guard result below)
                int other = skey[mc];
                if (m2 < NBOX && other == mykey[k]) win[k] = false;
            }
        }

        // ---- phase 3: winners recompute targets + gather pred + accumulate ----
        #pragma unroll
        for (int k = 0; k < 5; k++) {
            if (!win[k]) continue;
            int n = t + k * 256;
            float4 g = ((const float4*)gbox)[n];
            float gx = g.x * 0.125f;
            float gy = g.y * 0.125f;
            float gw = g.z * 0.125f;
            float gh = g.w * 0.125f;
            int gi = (int)gx, gj = (int)gy;
            int best = 0; float bestr = -1.f, baw = 1.f, bah = 1.f;
            #pragma unroll
            for (int a = 0; a < 3; a++) {
                float aw = anch[a * 2 + 0] * 0.125f;
                float ah = anch[a * 2 + 1] * 0.125f;
                float inter = fminf(aw, gw) * fminf(ah, gh);
                float uni   = aw * ah + gw * gh - inter;
                float r     = inter / uni;
                if (r > bestr) { bestr = r; best = a; baw = aw; bah = ah; }
            }
            float tx = gx - (float)gi;
            float ty = gy - (float)gj;
            float tw = __logf(gw / baw);
            float th = __logf(gh / bah);
            int b = bidx[n];
            long base = ((((long)b * GVAL + gj) * GVAL) + gi) * 15 + best * 5;
            float conf = yp[base + 0];
            float px = 1.f / (1.f + __expf(-yp[base + 1]));
            float py = 1.f / (1.f + __expf(-yp[base + 2]));
            float pw = yp[base + 3];
            float ph = yp[base + 4];
            float dx = px - tx, dy = py - ty, dw = pw - tw, dh = ph - th;
            float lp = __logf(1.f + __expf(-fabsf(conf)));
            float sp_pos = fmaxf( conf, 0.f) + lp;   // softplus(conf)
            float sp_neg = fmaxf(-conf, 0.f) + lp;   // softplus(-conf)
            acc += 5.f * (dx * dx + dy * dy + dw * dw + dh * dh)
                 + sp_neg - 0.5f * sp_pos;           // obj minus over-counted noobj
        }
    } else {
        // ---- noobj sweep: 0.5 * sum softplus(words ≡ 0 mod 5) ----
        // 16 coalesced float4 loads issued up front (all in flight), then fold.
        // Conf logits are every 5th word; float4 m holds one conf at component
        // j = m % 5 (none when j==4); k-step 256 ≡ 1 (mod 5) so j advances by +1.
        const float4* src = (const float4*)yp + (long)(blockIdx.x - 1) * SPAN_V4;
        float4 v[16];
        #pragma unroll
        for (int k = 0; k < 16; k++) v[k] = src[t + k * 256];

        int j = ((blockIdx.x - 1) * SPAN_V4 + t) % 5;
        float lacc = 0.f;
        #pragma unroll
        for (int k = 0; k < 16; k++) {
            float c  = (j == 0) ? v[k].x
                     : (j == 1) ? v[k].y
                     : (j == 2) ? v[k].z
                     :            v[k].w;
            float sp = softplus_f(c);
            lacc += (j < 4) ? sp : 0.f;              // j==4: float4 holds no conf
            j = (j == 4) ? 0 : j + 1;
        }
        acc = 0.5f * lacc;
    }
    return acc;
}

__device__ __forceinline__ float block_reduce(float acc) {
    __shared__ float swave[4];
    const int t = threadIdx.x;
    __syncthreads();                                 // guard swave reuse across calls
    #pragma unroll
    for (int off = 32; off > 0; off >>= 1) acc += __shfl_down(acc, off, 64);
    int lane = t & 63, wid = t >> 6;
    if (lane == 0) swave[wid] = acc;
    __syncthreads();
    return swave[0] + swave[1] + swave[2] + swave[3];   // valid in all threads
}

__global__ void __launch_bounds__(256) yolo_fused_kernel(
    const float* __restrict__ yp,
    const float* __restrict__ gbox,
    const float* __restrict__ anch,
    const int*   __restrict__ bidx,
    u64*         __restrict__ slot,
    float*       __restrict__ out)
{
    const int t = threadIdx.x;
    float acc  = yolo_body(yp, gbox, anch, bidx);
    float bsum = block_reduce(acc);

    if (blockIdx.x != 0) {
        if (t == 0) {
            u64 p = ((u64)TAG << 32) | (u64)__float_as_uint(bsum);
            __hip_atomic_store(&slot[blockIdx.x], p,
                               __ATOMIC_RELAXED, __HIP_MEMORY_SCOPE_AGENT);
        }
        return;
    }

    // ---- block 0: polling reduce, summation order IDENTICAL to the old
    // final_reduce_kernel (thread t: i = t, t+256, t+512, t+768; i==0 is our
    // own bsum) -> bit-exact result. 4 waves polling L3 slots: gentle.
    float a2 = 0.f;
    for (int i = t; i < NBLK; i += 256) {
        float term;
        if (i == 0) {
            term = bsum;
        } else {
            u64 v = __hip_atomic_load(&slot[i], __ATOMIC_RELAXED,
                                      __HIP_MEMORY_SCOPE_AGENT);
            while ((unsigned)(v >> 32) != (unsigned)TAG) {
                __builtin_amdgcn_s_sleep(8);
                v = __hip_atomic_load(&slot[i], __ATOMIC_RELAXED,
                                      __HIP_MEMORY_SCOPE_AGENT);
            }
            term = __uint_as_float((unsigned)v);
        }
        a2 += term;
    }
    float total = block_reduce(a2);
    if (t == 0) out[0] = total;   // plain store overwrites the 0xAA poison
}

extern "C" void kernel_launch(void* const* d_in, const int* in_sizes, int n_in,
                              void* d_out, int out_size, void* d_ws, size_t ws_size,
                              hipStream_t stream) {
    const float* yp   = (const float*)d_in[0];   // y_pred (B,G,G,15) fp32
    const float* gbox = (const float*)d_in[1];   // ground_bboxes (N,4) fp32
    const float* anch = (const float*)d_in[2];   // anchors (3,2) fp32
    const int*   bidx = (const int*)d_in[3];     // batch_idx (N,) int32
    u64*  slot = (u64*)d_ws;                     // NBLK publish slots (7688 B)
    float* outp = (float*)d_out;

    yolo_fused_kernel<<<dim3(NBLK), dim3(256), 0, stream>>>(yp, gbox, anch, bidx,
                                                            slot, outp);
}